// Round 1
// baseline (857.199 us; speedup 1.0000x reference)
//
#include <hip/hip_runtime.h>

#define NN   100000
#define TL   128
#define OC   5
#define KW   7
#define ST   3
#define CL   41          // (128-7)/3+1
#define FLAT 205         // 5*41
#define EMB  32
#define HID  16
#define NE   3200000

// ---------------------------------------------------------------------------
// Kernel 1: per-node temporal conv + FC + projection p1 = h32 @ g1w1^T
// One wave (64 lanes) per node; 4 waves per 256-thread block.
// ---------------------------------------------------------------------------
__global__ __launch_bounds__(256) void k_embed(
    const float* __restrict__ x,
    const float* __restrict__ conv_w, const float* __restrict__ conv_b,
    const float* __restrict__ fc_w,   const float* __restrict__ fc_b,
    const float* __restrict__ g1w1,
    float* __restrict__ p1)
{
    __shared__ float s_x[4][TL];        // staged x row per wave
    __shared__ float s_h[4][FLAT + 3];  // conv output (relu'd), padded
    __shared__ float s_e[4][EMB];       // fc output

    const int w    = threadIdx.x >> 6;
    const int lane = threadIdx.x & 63;
    const int node = blockIdx.x * 4 + w;   // NN % 4 == 0, no tail

    // coalesced load of x row: 64 lanes x float2 = 128 floats
    const float2* xr = (const float2*)(x + (size_t)node * TL);
    float2 v = xr[lane];
    s_x[w][lane * 2 + 0] = v.x;
    s_x[w][lane * 2 + 1] = v.y;
    __syncthreads();

    // conv1d + relu, channel-major flatten o = c*41 + t
    for (int o = lane; o < FLAT; o += 64) {
        int c = o / CL;
        int t = o - c * CL;
        float acc = conv_b[c];
        #pragma unroll
        for (int k = 0; k < KW; ++k)
            acc += s_x[w][t * ST + k] * conv_w[c * KW + k];
        s_h[w][o] = fmaxf(acc, 0.f);
    }
    __syncthreads();

    // fc: lane l < 32 computes output l (no activation after fc)
    if (lane < EMB) {
        float acc = fc_b[lane];
        const float* wr = fc_w + lane * FLAT;
        for (int j = 0; j < FLAT; ++j)
            acc += s_h[w][j] * wr[j];
        s_e[w][lane] = acc;
    }
    __syncthreads();

    // p1 = h32 @ g1w1^T  (bias NOT baked in — added after aggregation)
    if (lane < HID) {
        float acc = 0.f;
        const float* wr = g1w1 + lane * EMB;
        #pragma unroll
        for (int j = 0; j < EMB; ++j)
            acc += s_e[w][j] * wr[j];
        p1[(size_t)node * HID + lane] = acc;
    }
}

// ---------------------------------------------------------------------------
// Scatter: agg[dst] += p[src], 16 threads per edge (one component each).
// Gather of p[src*16..+15] is a coalesced 64B read across the 16 lanes.
// ---------------------------------------------------------------------------
__global__ __launch_bounds__(256) void k_scatter(
    const float* __restrict__ p, const int* __restrict__ ei,
    float* __restrict__ agg)
{
    long long t = (long long)blockIdx.x * 256 + threadIdx.x;
    int e = (int)(t >> 4);
    int k = (int)(t & 15);
    if (e >= NE) return;
    int src = ei[e];
    int dst = ei[NE + e];
    float v = p[(size_t)src * HID + k];
    atomicAdd(agg + (size_t)dst * HID + k, v);
}

// ---------------------------------------------------------------------------
// GIN layer 1 epilogue + layer 2 projection:
//   t  = relu(p1 + agg + b1)
//   h1 = relu(t @ g1w2^T + b2)        (ReLU between GIN layers)
//   p2 = h1 @ g2w1^T                  (written over p1 buffer — safe per-thread)
// ---------------------------------------------------------------------------
__global__ __launch_bounds__(256) void k_mlp1(
    const float* __restrict__ p1, const float* __restrict__ agg,
    const float* __restrict__ b1, const float* __restrict__ w2,
    const float* __restrict__ b2, const float* __restrict__ w3,
    float* __restrict__ p2)
{
    __shared__ float s_w2[HID * HID], s_w3[HID * HID], s_b1[HID], s_b2[HID];
    int tid = threadIdx.x;
    s_w2[tid % (HID * HID)] = w2[tid % (HID * HID)];  // 256 threads == 256 elems
    s_w3[tid % (HID * HID)] = w3[tid % (HID * HID)];
    if (tid < HID) { s_b1[tid] = b1[tid]; s_b2[tid] = b2[tid]; }
    __syncthreads();

    int n = blockIdx.x * 256 + tid;
    if (n >= NN) return;

    float t[HID], h[HID];
    const float4* pa = (const float4*)(p1  + (size_t)n * HID);
    const float4* pb = (const float4*)(agg + (size_t)n * HID);
    #pragma unroll
    for (int i = 0; i < 4; ++i) {
        float4 a = pa[i], b = pb[i];
        t[i*4+0] = fmaxf(a.x + b.x + s_b1[i*4+0], 0.f);
        t[i*4+1] = fmaxf(a.y + b.y + s_b1[i*4+1], 0.f);
        t[i*4+2] = fmaxf(a.z + b.z + s_b1[i*4+2], 0.f);
        t[i*4+3] = fmaxf(a.w + b.w + s_b1[i*4+3], 0.f);
    }
    #pragma unroll
    for (int i = 0; i < HID; ++i) {
        float acc = s_b2[i];
        #pragma unroll
        for (int j = 0; j < HID; ++j) acc += t[j] * s_w2[i * HID + j];
        h[i] = fmaxf(acc, 0.f);
    }
    float o[HID];
    #pragma unroll
    for (int i = 0; i < HID; ++i) {
        float acc = 0.f;
        #pragma unroll
        for (int j = 0; j < HID; ++j) acc += h[j] * s_w3[i * HID + j];
        o[i] = acc;
    }
    float4* po = (float4*)(p2 + (size_t)n * HID);
    #pragma unroll
    for (int i = 0; i < 4; ++i)
        po[i] = make_float4(o[i*4+0], o[i*4+1], o[i*4+2], o[i*4+3]);
}

// ---------------------------------------------------------------------------
// Final: t2 = relu(p2 + agg2 + g2b1); h2 = t2 @ g2w2^T + g2b2 (no relu);
//        out = h2 . ro_w + ro_b
// ---------------------------------------------------------------------------
__global__ __launch_bounds__(256) void k_final(
    const float* __restrict__ p2, const float* __restrict__ agg2,
    const float* __restrict__ b1, const float* __restrict__ w2,
    const float* __restrict__ b2, const float* __restrict__ row,
    const float* __restrict__ rob,
    float* __restrict__ out)
{
    __shared__ float s_w2[HID * HID], s_b1[HID], s_b2[HID], s_ro[HID];
    int tid = threadIdx.x;
    s_w2[tid % (HID * HID)] = w2[tid % (HID * HID)];
    if (tid < HID) { s_b1[tid] = b1[tid]; s_b2[tid] = b2[tid]; s_ro[tid] = row[tid]; }
    __syncthreads();

    int n = blockIdx.x * 256 + tid;
    if (n >= NN) return;

    float t[HID];
    const float4* pa = (const float4*)(p2   + (size_t)n * HID);
    const float4* pb = (const float4*)(agg2 + (size_t)n * HID);
    #pragma unroll
    for (int i = 0; i < 4; ++i) {
        float4 a = pa[i], b = pb[i];
        t[i*4+0] = fmaxf(a.x + b.x + s_b1[i*4+0], 0.f);
        t[i*4+1] = fmaxf(a.y + b.y + s_b1[i*4+1], 0.f);
        t[i*4+2] = fmaxf(a.z + b.z + s_b1[i*4+2], 0.f);
        t[i*4+3] = fmaxf(a.w + b.w + s_b1[i*4+3], 0.f);
    }
    float res = rob[0];
    #pragma unroll
    for (int i = 0; i < HID; ++i) {
        float acc = s_b2[i];
        #pragma unroll
        for (int j = 0; j < HID; ++j) acc += t[j] * s_w2[i * HID + j];
        res += acc * s_ro[i];           // no relu on final GIN output
    }
    out[n] = res;
}

// ---------------------------------------------------------------------------
extern "C" void kernel_launch(void* const* d_in, const int* in_sizes, int n_in,
                              void* d_out, int out_size, void* d_ws, size_t ws_size,
                              hipStream_t stream)
{
    const float* x      = (const float*)d_in[0];
    const int*   ei     = (const int*)  d_in[1];
    const float* conv_w = (const float*)d_in[2];
    const float* conv_b = (const float*)d_in[3];
    const float* fc_w   = (const float*)d_in[4];
    const float* fc_b   = (const float*)d_in[5];
    const float* g1w1   = (const float*)d_in[6];
    const float* g1b1   = (const float*)d_in[7];
    const float* g1w2   = (const float*)d_in[8];
    const float* g1b2   = (const float*)d_in[9];
    const float* g2w1   = (const float*)d_in[10];
    const float* g2b1   = (const float*)d_in[11];
    const float* g2w2   = (const float*)d_in[12];
    const float* g2b2   = (const float*)d_in[13];
    const float* ro_w   = (const float*)d_in[14];
    const float* ro_b   = (const float*)d_in[15];
    float* out = (float*)d_out;

    float* A = (float*)d_ws;               // N x 16 projected features
    float* B = A + (size_t)NN * HID;       // N x 16 aggregation buffer

    // node embedding + layer-1 projection
    k_embed<<<NN / 4, 256, 0, stream>>>(x, conv_w, conv_b, fc_w, fc_b, g1w1, A);

    // GIN layer 1 aggregation
    hipMemsetAsync(B, 0, (size_t)NN * HID * sizeof(float), stream);
    k_scatter<<<(int)(((long long)NE * HID) / 256), 256, 0, stream>>>(A, ei, B);

    // layer-1 MLP + layer-2 projection (A <- p2)
    k_mlp1<<<(NN + 255) / 256, 256, 0, stream>>>(A, B, g1b1, g1w2, g1b2, g2w1, A);

    // GIN layer 2 aggregation
    hipMemsetAsync(B, 0, (size_t)NN * HID * sizeof(float), stream);
    k_scatter<<<(int)(((long long)NE * HID) / 256), 256, 0, stream>>>(A, ei, B);

    // layer-2 MLP + readout
    k_final<<<(NN + 255) / 256, 256, 0, stream>>>(A, B, g2b1, g2w2, g2b2,
                                                  ro_w, ro_b, out);
}

// Round 2
// 565.074 us; speedup vs baseline: 1.5170x; 1.5170x over previous
//
#include <hip/hip_runtime.h>

#define NN   100000
#define TL   128
#define OC   5
#define KW   7
#define ST   3
#define CL   41          // (128-7)/3+1
#define FLAT 205         // 5*41
#define EMB  32
#define HID  16
#define NE   3200000

// ===========================================================================
// FAST PATH (needs ~95 MB workspace)
// ===========================================================================

// ---------------------------------------------------------------------------
// Precompute combined weight Wc = g1w1 @ fc_w  ([16 x 205], stored transposed
// j-major as wcT[j*16+l]) and bc = g1w1 @ fc_b ([16]).  One block, trivial.
// ---------------------------------------------------------------------------
__global__ __launch_bounds__(256) void k_prep(
    const float* __restrict__ g1w1, const float* __restrict__ fc_w,
    const float* __restrict__ fc_b,
    float* __restrict__ wcT, float* __restrict__ bc)
{
    int tid = threadIdx.x;
    for (int idx = tid; idx < FLAT * HID; idx += 256) {
        int l = idx & 15;
        int j = idx >> 4;
        float s = 0.f;
        #pragma unroll
        for (int m = 0; m < EMB; ++m)
            s = fmaf(g1w1[l * EMB + m], fc_w[m * FLAT + j], s);
        wcT[j * HID + l] = s;
    }
    if (tid < HID) {
        float s = 0.f;
        #pragma unroll
        for (int m = 0; m < EMB; ++m)
            s = fmaf(g1w1[tid * EMB + m], fc_b[m], s);
        bc[tid] = s;
    }
}

// ---------------------------------------------------------------------------
// Conv1d + ReLU -> Ht[o][n] (j-major so the FC kernel reads coalesced).
// 64-node tile per block; x rows staged in LDS with pad 129 (conflict-free:
// read addr = n*129 + t*3+k -> bank (n + c) mod 32, 2-way max = free).
// ---------------------------------------------------------------------------
__global__ __launch_bounds__(256) void k_conv(
    const float* __restrict__ x,
    const float* __restrict__ conv_w, const float* __restrict__ conv_b,
    float* __restrict__ Ht)
{
    __shared__ float s_x[64 * 129];
    const int tid = threadIdx.x;
    const long long n0 = (long long)blockIdx.x * 64;
    const int nvalid = min(64, NN - (int)n0);

    // stage 64 x-rows: 2048 float4 loads, coalesced; row-padded LDS writes
    const float4* xv = (const float4*)(x + n0 * TL);
    #pragma unroll
    for (int c = 0; c < 8; ++c) {
        int f4  = c * 256 + tid;      // 0..2047
        int row = f4 >> 5;            // 32 float4 per 128-float row
        int c4  = f4 & 31;
        if (row < nvalid) {
            float4 v = xv[f4];
            float* d = s_x + row * 129 + c4 * 4;
            d[0] = v.x; d[1] = v.y; d[2] = v.z; d[3] = v.w;
        }
    }
    __syncthreads();

    // 205*64 outputs; o = idx>>6 is wave-uniform -> conv_w/conv_b scalar loads
    for (int idx = tid; idx < FLAT * 64; idx += 256) {
        int n = idx & 63;
        int o = idx >> 6;
        int c = o / CL;
        int t = o - c * CL;
        float acc = conv_b[c];
        const float* wr = conv_w + c * KW;
        const float* xr = s_x + n * 129 + t * ST;
        #pragma unroll
        for (int k = 0; k < KW; ++k)
            acc = fmaf(xr[k], wr[k], acc);
        if (n < nvalid)
            Ht[(size_t)o * NN + n0 + n] = fmaxf(acc, 0.f);
    }
}

// ---------------------------------------------------------------------------
// FC (fused with g1w1): p1[n][l] = bc[l] + sum_j Ht[j][n] * wcT[j][l].
// Thread-per-node; Ht reads coalesced, weight reads wave-uniform.
// ---------------------------------------------------------------------------
__global__ __launch_bounds__(256) void k_fc(
    const float* __restrict__ Ht, const float* __restrict__ wcT,
    const float* __restrict__ bc, float* __restrict__ p1)
{
    int n = blockIdx.x * 256 + threadIdx.x;
    if (n >= NN) return;

    float acc[HID];
    #pragma unroll
    for (int l = 0; l < HID; ++l) acc[l] = bc[l];

    #pragma unroll 5
    for (int j = 0; j < FLAT; ++j) {
        float h = Ht[(size_t)j * NN + n];
        const float* w = wcT + j * HID;
        #pragma unroll
        for (int l = 0; l < HID; ++l)
            acc[l] = fmaf(h, w[l], acc[l]);
    }

    float4* po = (float4*)(p1 + (size_t)n * HID);
    po[0] = make_float4(acc[0],  acc[1],  acc[2],  acc[3]);
    po[1] = make_float4(acc[4],  acc[5],  acc[6],  acc[7]);
    po[2] = make_float4(acc[8],  acc[9],  acc[10], acc[11]);
    po[3] = make_float4(acc[12], acc[13], acc[14], acc[15]);
}

// ===========================================================================
// FALLBACK PATH (round-1 k_embed, used only if workspace is too small)
// ===========================================================================
__global__ __launch_bounds__(256) void k_embed(
    const float* __restrict__ x,
    const float* __restrict__ conv_w, const float* __restrict__ conv_b,
    const float* __restrict__ fc_w,   const float* __restrict__ fc_b,
    const float* __restrict__ g1w1,
    float* __restrict__ p1)
{
    __shared__ float s_x[4][TL];
    __shared__ float s_h[4][FLAT + 3];
    __shared__ float s_e[4][EMB];

    const int w    = threadIdx.x >> 6;
    const int lane = threadIdx.x & 63;
    const int node = blockIdx.x * 4 + w;

    const float2* xr = (const float2*)(x + (size_t)node * TL);
    float2 v = xr[lane];
    s_x[w][lane * 2 + 0] = v.x;
    s_x[w][lane * 2 + 1] = v.y;
    __syncthreads();

    for (int o = lane; o < FLAT; o += 64) {
        int c = o / CL;
        int t = o - c * CL;
        float acc = conv_b[c];
        #pragma unroll
        for (int k = 0; k < KW; ++k)
            acc += s_x[w][t * ST + k] * conv_w[c * KW + k];
        s_h[w][o] = fmaxf(acc, 0.f);
    }
    __syncthreads();

    if (lane < EMB) {
        float acc = fc_b[lane];
        const float* wr = fc_w + lane * FLAT;
        for (int j = 0; j < FLAT; ++j)
            acc += s_h[w][j] * wr[j];
        s_e[w][lane] = acc;
    }
    __syncthreads();

    if (lane < HID) {
        float acc = 0.f;
        const float* wr = g1w1 + lane * EMB;
        #pragma unroll
        for (int j = 0; j < EMB; ++j)
            acc += s_e[w][j] * wr[j];
        p1[(size_t)node * HID + lane] = acc;
    }
}

// ===========================================================================
// Shared kernels (scatter / MLP / final) — unchanged from round 1
// ===========================================================================
__global__ __launch_bounds__(256) void k_scatter(
    const float* __restrict__ p, const int* __restrict__ ei,
    float* __restrict__ agg)
{
    long long t = (long long)blockIdx.x * 256 + threadIdx.x;
    int e = (int)(t >> 4);
    int k = (int)(t & 15);
    if (e >= NE) return;
    int src = ei[e];
    int dst = ei[NE + e];
    float v = p[(size_t)src * HID + k];
    atomicAdd(agg + (size_t)dst * HID + k, v);
}

__global__ __launch_bounds__(256) void k_mlp1(
    const float* __restrict__ p1, const float* __restrict__ agg,
    const float* __restrict__ b1, const float* __restrict__ w2,
    const float* __restrict__ b2, const float* __restrict__ w3,
    float* __restrict__ p2)
{
    __shared__ float s_w2[HID * HID], s_w3[HID * HID], s_b1[HID], s_b2[HID];
    int tid = threadIdx.x;
    s_w2[tid] = w2[tid];
    s_w3[tid] = w3[tid];
    if (tid < HID) { s_b1[tid] = b1[tid]; s_b2[tid] = b2[tid]; }
    __syncthreads();

    int n = blockIdx.x * 256 + tid;
    if (n >= NN) return;

    float t[HID], h[HID];
    const float4* pa = (const float4*)(p1  + (size_t)n * HID);
    const float4* pb = (const float4*)(agg + (size_t)n * HID);
    #pragma unroll
    for (int i = 0; i < 4; ++i) {
        float4 a = pa[i], b = pb[i];
        t[i*4+0] = fmaxf(a.x + b.x + s_b1[i*4+0], 0.f);
        t[i*4+1] = fmaxf(a.y + b.y + s_b1[i*4+1], 0.f);
        t[i*4+2] = fmaxf(a.z + b.z + s_b1[i*4+2], 0.f);
        t[i*4+3] = fmaxf(a.w + b.w + s_b1[i*4+3], 0.f);
    }
    #pragma unroll
    for (int i = 0; i < HID; ++i) {
        float acc = s_b2[i];
        #pragma unroll
        for (int j = 0; j < HID; ++j) acc += t[j] * s_w2[i * HID + j];
        h[i] = fmaxf(acc, 0.f);
    }
    float o[HID];
    #pragma unroll
    for (int i = 0; i < HID; ++i) {
        float acc = 0.f;
        #pragma unroll
        for (int j = 0; j < HID; ++j) acc += h[j] * s_w3[i * HID + j];
        o[i] = acc;
    }
    float4* po = (float4*)(p2 + (size_t)n * HID);
    #pragma unroll
    for (int i = 0; i < 4; ++i)
        po[i] = make_float4(o[i*4+0], o[i*4+1], o[i*4+2], o[i*4+3]);
}

__global__ __launch_bounds__(256) void k_final(
    const float* __restrict__ p2, const float* __restrict__ agg2,
    const float* __restrict__ b1, const float* __restrict__ w2,
    const float* __restrict__ b2, const float* __restrict__ row,
    const float* __restrict__ rob,
    float* __restrict__ out)
{
    __shared__ float s_w2[HID * HID], s_b1[HID], s_b2[HID], s_ro[HID];
    int tid = threadIdx.x;
    s_w2[tid] = w2[tid];
    if (tid < HID) { s_b1[tid] = b1[tid]; s_b2[tid] = b2[tid]; s_ro[tid] = row[tid]; }
    __syncthreads();

    int n = blockIdx.x * 256 + tid;
    if (n >= NN) return;

    float t[HID];
    const float4* pa = (const float4*)(p2   + (size_t)n * HID);
    const float4* pb = (const float4*)(agg2 + (size_t)n * HID);
    #pragma unroll
    for (int i = 0; i < 4; ++i) {
        float4 a = pa[i], b = pb[i];
        t[i*4+0] = fmaxf(a.x + b.x + s_b1[i*4+0], 0.f);
        t[i*4+1] = fmaxf(a.y + b.y + s_b1[i*4+1], 0.f);
        t[i*4+2] = fmaxf(a.z + b.z + s_b1[i*4+2], 0.f);
        t[i*4+3] = fmaxf(a.w + b.w + s_b1[i*4+3], 0.f);
    }
    float res = rob[0];
    #pragma unroll
    for (int i = 0; i < HID; ++i) {
        float acc = s_b2[i];
        #pragma unroll
        for (int j = 0; j < HID; ++j) acc += t[j] * s_w2[i * HID + j];
        res += acc * s_ro[i];
    }
    out[n] = res;
}

// ===========================================================================
extern "C" void kernel_launch(void* const* d_in, const int* in_sizes, int n_in,
                              void* d_out, int out_size, void* d_ws, size_t ws_size,
                              hipStream_t stream)
{
    const float* x      = (const float*)d_in[0];
    const int*   ei     = (const int*)  d_in[1];
    const float* conv_w = (const float*)d_in[2];
    const float* conv_b = (const float*)d_in[3];
    const float* fc_w   = (const float*)d_in[4];
    const float* fc_b   = (const float*)d_in[5];
    const float* g1w1   = (const float*)d_in[6];
    const float* g1b1   = (const float*)d_in[7];
    const float* g1w2   = (const float*)d_in[8];
    const float* g1b2   = (const float*)d_in[9];
    const float* g2w1   = (const float*)d_in[10];
    const float* g2b1   = (const float*)d_in[11];
    const float* g2w2   = (const float*)d_in[12];
    const float* g2b2   = (const float*)d_in[13];
    const float* ro_w   = (const float*)d_in[14];
    const float* ro_b   = (const float*)d_in[15];
    float* out = (float*)d_out;

    // workspace layout (floats):
    //   A   [NN*HID]        projected features
    //   B   [NN*HID]        aggregation buffer
    //   wcT [FLAT*HID]      combined fc+g1w1 weight, j-major
    //   bc  [16]            combined bias
    //   Ht  [FLAT*NN]       conv output, j-major
    float* A   = (float*)d_ws;
    float* B   = A + (size_t)NN * HID;
    float* wcT = B + (size_t)NN * HID;
    float* bc  = wcT + (size_t)FLAT * HID;
    float* Ht  = bc + 16;
    const size_t need = ((size_t)NN * HID * 2 + (size_t)FLAT * HID + 16 +
                         (size_t)FLAT * NN) * sizeof(float);

    if (ws_size >= need) {
        k_prep<<<1, 256, 0, stream>>>(g1w1, fc_w, fc_b, wcT, bc);
        k_conv<<<(NN + 63) / 64, 256, 0, stream>>>(x, conv_w, conv_b, Ht);
        k_fc<<<(NN + 255) / 256, 256, 0, stream>>>(Ht, wcT, bc, A);
    } else {
        k_embed<<<NN / 4, 256, 0, stream>>>(x, conv_w, conv_b, fc_w, fc_b,
                                            g1w1, A);
    }

    // GIN layer 1 aggregation (on projected 16-dim features)
    hipMemsetAsync(B, 0, (size_t)NN * HID * sizeof(float), stream);
    k_scatter<<<(int)(((long long)NE * HID) / 256), 256, 0, stream>>>(A, ei, B);

    // layer-1 MLP epilogue + layer-2 projection (A <- p2)
    k_mlp1<<<(NN + 255) / 256, 256, 0, stream>>>(A, B, g1b1, g1w2, g1b2, g2w1, A);

    // GIN layer 2 aggregation
    hipMemsetAsync(B, 0, (size_t)NN * HID * sizeof(float), stream);
    k_scatter<<<(int)(((long long)NE * HID) / 256), 256, 0, stream>>>(A, ei, B);

    // layer-2 MLP + readout
    k_final<<<(NN + 255) / 256, 256, 0, stream>>>(A, B, g2b1, g2w2, g2b2,
                                                  ro_w, ro_b, out);
}